// Round 2
// baseline (777.217 us; speedup 1.0000x reference)
//
#include <hip/hip_runtime.h>
#include <hip/hip_bf16.h>
#include <stdint.h>

typedef unsigned short u16;
typedef __attribute__((ext_vector_type(8))) short bf16x8;          // 8 bf16 in 4 VGPRs
typedef __attribute__((ext_vector_type(8))) unsigned short u16x8;  // 16B store unit
typedef __attribute__((ext_vector_type(4))) float f32x4;

#define NTOK 49
#define CDIM 256
#define NHEAD 8
#define HDIM 32
#define MWIN 64
#define SCALE_F 0.17677669529663687f  /* 32^-0.5 */

static __device__ inline u16 f2b(float f) {
    union { float f; unsigned u; } v; v.f = f;
    unsigned r = v.u + 0x7fff + ((v.u >> 16) & 1);   // RNE
    return (u16)(r >> 16);
}

// ---------------------------------------------------------------------------
// fp32 -> bf16 converter, 8 elements/thread (two float4 loads, one 16B store)
// ---------------------------------------------------------------------------
__global__ __launch_bounds__(256) void conv_bf16(
    const float* __restrict__ src, u16* __restrict__ dst, int n8)
{
    int i = blockIdx.x * 256 + threadIdx.x;
    if (i < n8) {
        float4 a = ((const float4*)src)[2 * i];
        float4 b = ((const float4*)src)[2 * i + 1];
        u16x8 v;
        v[0] = f2b(a.x); v[1] = f2b(a.y); v[2] = f2b(a.z); v[3] = f2b(a.w);
        v[4] = f2b(b.x); v[5] = f2b(b.y); v[6] = f2b(b.z); v[7] = f2b(b.w);
        ((u16x8*)dst)[i] = v;
    }
}

// ---------------------------------------------------------------------------
// comb[m][h][64][64] = bias_table[rel_index[i,j], h] + mask[m,i,j], fp32.
// Padding (i>=49 || j>=49) = -1e9 so softmax sees exp(..)=0.
// ---------------------------------------------------------------------------
__global__ __launch_bounds__(256) void build_comb(
    const float* __restrict__ bias_table,   // [169,8] fp32
    const float* __restrict__ mask,         // [64,49,49] fp32
    const int*   __restrict__ rel_index,    // [49,49] int32
    float* __restrict__ comb)               // [64,8,64,64]
{
    int idx = blockIdx.x * 256 + threadIdx.x;       // 64*8*64*64 = 2097152
    int j = idx & 63, i = (idx >> 6) & 63, h = (idx >> 12) & 7, m = idx >> 15;
    float v = -1e9f;
    if (i < NTOK && j < NTOK) {
        int rel = rel_index[i * NTOK + j];
        v = bias_table[rel * NHEAD + h] + mask[m * (NTOK * NTOK) + i * NTOK + j];
    }
    comb[idx] = v;
}

// ---------------------------------------------------------------------------
// QKV projection: C[rows,768] = A[rows,256] @ W^T + b  (bf16 in, fp32 acc,
// bf16 out). 128x128 tile, BK=64, 4 waves (2x2), each wave 64x64 via 4x4
// grid of mfma_f32_16x16x32_bf16. LDS row stride 72 elems = 144B.
// ---------------------------------------------------------------------------
__global__ __launch_bounds__(256) void qkv_gemm(
    const u16*  __restrict__ A,     // [rows,256] bf16 (pre-converted chunk)
    const u16*  __restrict__ Wt,    // [768,256]  bf16 (pre-converted)
    const float* __restrict__ bias, // [768] fp32
    u16* __restrict__ Cout)         // [rows,768] bf16
{
    __shared__ u16 As[128 * 72];
    __shared__ u16 Bs[128 * 72];

    const int t = threadIdx.x;
    const int bm = blockIdx.x, bn = blockIdx.y;
    const int wave = t >> 6, lane = t & 63;
    const int wm = wave >> 1, wn = wave & 1;
    const int lrow = lane & 15, quad = lane >> 4;

    f32x4 acc[4][4];
#pragma unroll
    for (int i = 0; i < 4; i++)
#pragma unroll
        for (int j = 0; j < 4; j++) acc[i][j] = (f32x4){0.f, 0.f, 0.f, 0.f};

    const int srow = t >> 3;    // 0..31
    const int part = t & 7;     // 0..7 (16B chunk within 64-elem row slice)
    const u16* Ab = A  + (size_t)(bm * 128) * CDIM + part * 8;
    const u16* Bb = Wt + (size_t)(bn * 128) * CDIM + part * 8;

#pragma unroll
    for (int kt = 0; kt < 4; kt++) {
        if (kt) __syncthreads();
        const int k0 = kt * 64;
#pragma unroll
        for (int r = 0; r < 4; r++) {
            int row = r * 32 + srow;
            *(int4*)&As[row * 72 + part * 8] = *(const int4*)&Ab[(size_t)row * CDIM + k0];
            *(int4*)&Bs[row * 72 + part * 8] = *(const int4*)&Bb[(size_t)row * CDIM + k0];
        }
        __syncthreads();
#pragma unroll
        for (int kk = 0; kk < 2; kk++) {
            const int kb = kk * 32 + quad * 8;
            bf16x8 af[4], bfr[4];
#pragma unroll
            for (int tm = 0; tm < 4; tm++)
                af[tm] = *(const bf16x8*)&As[(wm * 64 + tm * 16 + lrow) * 72 + kb];
#pragma unroll
            for (int tn = 0; tn < 4; tn++)
                bfr[tn] = *(const bf16x8*)&Bs[(wn * 64 + tn * 16 + lrow) * 72 + kb];
#pragma unroll
            for (int tm = 0; tm < 4; tm++)
#pragma unroll
                for (int tn = 0; tn < 4; tn++)
                    acc[tm][tn] = __builtin_amdgcn_mfma_f32_16x16x32_bf16(
                        af[tm], bfr[tn], acc[tm][tn], 0, 0, 0);
        }
    }

    // epilogue: +bias, bf16 store. C/D layout: col=lane&15, row=quad*4+reg.
#pragma unroll
    for (int tn = 0; tn < 4; tn++) {
        int gcol = bn * 128 + wn * 64 + tn * 16 + lrow;
        float bv = bias[gcol];
#pragma unroll
        for (int tm = 0; tm < 4; tm++) {
            int grow0 = bm * 128 + wm * 64 + tm * 16 + quad * 4;
#pragma unroll
            for (int r = 0; r < 4; r++)
                Cout[(size_t)(grow0 + r) * 768 + gcol] = f2b(acc[tm][tn][r] + bv);
        }
    }
}

// ---------------------------------------------------------------------------
// Window attention: one wave per (window, head). 49 padded to 64.
// QK^T: 16 mfma (HD=32 = one K-step). Softmax via quad-group shfl_xor.
// P (bf16, normalized) -> LDS, PV with V stored transposed.
// LDS: q[64x40] k[64x40] vT[32x72]; P[64x72] aliases dead q/k region.
// ---------------------------------------------------------------------------
__global__ __launch_bounds__(64) void win_attn(
    const u16*   __restrict__ qkv,   // [Wchunk*49, 768] bf16 chunk
    const float* __restrict__ comb,  // [64,8,64,64] fp32
    float* __restrict__ out,         // [4096,49,256] fp32
    int b0)                          // window offset of this chunk
{
    __shared__ u16 smem[7424];      // 14848 B
    u16* q    = smem;               // 64*40 = 2560
    u16* kbuf = smem + 2560;        // 64*40 = 2560
    u16* vT   = smem + 5120;        // 32*72 = 2304
    u16* P    = smem;               // 64*72 = 4608, overlays q + part of k

    const int lane = threadIdx.x;
    const int wloc = blockIdx.x;
    const int h = blockIdx.y;
    const int bg = b0 + wloc;
    const size_t rbase = (size_t)wloc * NTOK * 768;
    const int qoff = h * HDIM, koff = 256 + h * HDIM, voff = 512 + h * HDIM;

    // stage q, k: 49 tokens * 4 16B-chunks each
    for (int c = lane; c < NTOK * 4; c += 64) {
        int tok = c >> 2, p = (c & 3) * 8;
        *(int4*)&q[tok * 40 + p]    = *(const int4*)&qkv[rbase + (size_t)tok * 768 + qoff + p];
        *(int4*)&kbuf[tok * 40 + p] = *(const int4*)&qkv[rbase + (size_t)tok * 768 + koff + p];
    }
    // stage v transposed (scalar)
    for (int c = lane; c < NTOK * HDIM; c += 64) {
        int tok = c >> 5, d = c & 31;
        vT[d * 72 + tok] = qkv[rbase + (size_t)tok * 768 + voff + d];
    }
    // zero pads: q/k rows 49..63; vT token-cols 49..63
    for (int c = lane; c < 15 * 40; c += 64) { q[NTOK * 40 + c] = 0; kbuf[NTOK * 40 + c] = 0; }
    for (int c = lane; c < 32 * 15; c += 64) { int d = c / 15; vT[d * 72 + NTOK + (c % 15)] = 0; }
    __syncthreads();

    const int lrow = lane & 15, quad = lane >> 4;

    // ---- QK^T ----
    f32x4 s[4][4];
#pragma unroll
    for (int i = 0; i < 4; i++)
#pragma unroll
        for (int j = 0; j < 4; j++) s[i][j] = (f32x4){0.f, 0.f, 0.f, 0.f};
    {
        const int kb = quad * 8;
        bf16x8 af[4], bfr[4];
#pragma unroll
        for (int tm = 0; tm < 4; tm++) af[tm]  = *(const bf16x8*)&q[(tm * 16 + lrow) * 40 + kb];
#pragma unroll
        for (int tn = 0; tn < 4; tn++) bfr[tn] = *(const bf16x8*)&kbuf[(tn * 16 + lrow) * 40 + kb];
#pragma unroll
        for (int tm = 0; tm < 4; tm++)
#pragma unroll
            for (int tn = 0; tn < 4; tn++)
                s[tm][tn] = __builtin_amdgcn_mfma_f32_16x16x32_bf16(af[tm], bfr[tn], s[tm][tn], 0, 0, 0);
    }

    // ---- scale + bias + mask ----
    const float* cb = comb + (((size_t)(bg & (MWIN - 1)) * NHEAD + h) << 12);
#pragma unroll
    for (int tm = 0; tm < 4; tm++)
#pragma unroll
        for (int r = 0; r < 4; r++) {
            int i = tm * 16 + quad * 4 + r;
            const float* crow = cb + i * 64 + lrow;
#pragma unroll
            for (int tn = 0; tn < 4; tn++)
                s[tm][tn][r] = s[tm][tn][r] * SCALE_F + crow[tn * 16];
        }

    __syncthreads();   // all q/k frag reads done before P overwrites them

    // ---- softmax (rows live in 16-lane quad-groups) + write normalized P ----
#pragma unroll
    for (int tm = 0; tm < 4; tm++)
#pragma unroll
        for (int r = 0; r < 4; r++) {
            float mx = fmaxf(fmaxf(s[tm][0][r], s[tm][1][r]), fmaxf(s[tm][2][r], s[tm][3][r]));
            mx = fmaxf(mx, __shfl_xor(mx, 1));
            mx = fmaxf(mx, __shfl_xor(mx, 2));
            mx = fmaxf(mx, __shfl_xor(mx, 4));
            mx = fmaxf(mx, __shfl_xor(mx, 8));
            float e0 = __expf(s[tm][0][r] - mx);
            float e1 = __expf(s[tm][1][r] - mx);
            float e2 = __expf(s[tm][2][r] - mx);
            float e3 = __expf(s[tm][3][r] - mx);
            float sum = e0 + e1 + e2 + e3;
            sum += __shfl_xor(sum, 1);
            sum += __shfl_xor(sum, 2);
            sum += __shfl_xor(sum, 4);
            sum += __shfl_xor(sum, 8);
            float inv = 1.0f / sum;
            int i = tm * 16 + quad * 4 + r;
            P[i * 72 + lrow]      = f2b(e0 * inv);
            P[i * 72 + 16 + lrow] = f2b(e1 * inv);
            P[i * 72 + 32 + lrow] = f2b(e2 * inv);
            P[i * 72 + 48 + lrow] = f2b(e3 * inv);
        }
    __syncthreads();

    // ---- PV ----
    f32x4 o[4][2];
#pragma unroll
    for (int i = 0; i < 4; i++) { o[i][0] = (f32x4){0.f, 0.f, 0.f, 0.f}; o[i][1] = (f32x4){0.f, 0.f, 0.f, 0.f}; }
#pragma unroll
    for (int kk = 0; kk < 2; kk++) {
        const int kb = kk * 32 + quad * 8;
        bf16x8 pf[4], vf[2];
#pragma unroll
        for (int tm = 0; tm < 4; tm++) pf[tm] = *(const bf16x8*)&P[(tm * 16 + lrow) * 72 + kb];
#pragma unroll
        for (int tn = 0; tn < 2; tn++) vf[tn] = *(const bf16x8*)&vT[(tn * 16 + lrow) * 72 + kb];
#pragma unroll
        for (int tm = 0; tm < 4; tm++)
#pragma unroll
            for (int tn = 0; tn < 2; tn++)
                o[tm][tn] = __builtin_amdgcn_mfma_f32_16x16x32_bf16(pf[tm], vf[tn], o[tm][tn], 0, 0, 0);
    }

    // ---- store ctx (fp32): out[bg, i, h*32 + d] ----
    float* ob = out + (size_t)bg * NTOK * CDIM + h * HDIM;
#pragma unroll
    for (int tm = 0; tm < 4; tm++)
#pragma unroll
        for (int r = 0; r < 4; r++) {
            int i = tm * 16 + quad * 4 + r;
            if (i < NTOK) {
#pragma unroll
                for (int tn = 0; tn < 2; tn++)
                    ob[(size_t)i * CDIM + tn * 16 + lrow] = o[tm][tn][r];
            }
        }
}

// ---------------------------------------------------------------------------
extern "C" void kernel_launch(void* const* d_in, const int* in_sizes, int n_in,
                              void* d_out, int out_size, void* d_ws, size_t ws_size,
                              hipStream_t stream) {
    const float* hidden     = (const float*)d_in[0];   // [4096,49,256] fp32
    const float* mask       = (const float*)d_in[1];   // [64,49,49]    fp32
    const float* qkv_w      = (const float*)d_in[2];   // [768,256]     fp32
    const float* qkv_b      = (const float*)d_in[3];   // [768]         fp32
    const float* bias_table = (const float*)d_in[4];   // [169,8]       fp32
    const int*   rel_index  = (const int*)d_in[5];     // [49,49]       int32
    float* out = (float*)d_out;

    // ws layout: comb fp32 | W bf16 | hidden-chunk bf16 | qkv-chunk bf16
    float* comb = (float*)d_ws;                              // 8,388,608 B
    u16* wbuf = (u16*)((char*)d_ws + 8388608);               //   393,216 B
    // windows per chunk: multiple of 128 so GEMM rows % 128 == 0; cap 1024 to
    // keep bf16 scratch L3-resident.
    int W = 1024;
    while (W > 128 && 8781824ull + (size_t)W * NTOK * 2048 > ws_size) W >>= 1;
    int nch = 4096 / W;
    u16* hbuf = wbuf + 196608;                  // W*49*256 bf16 elems
    u16* qkvbuf = hbuf + (size_t)W * NTOK * CDIM;

    build_comb<<<dim3(2097152 / 256), dim3(256), 0, stream>>>(bias_table, mask, rel_index, comb);
    conv_bf16<<<dim3((196608 / 8 + 255) / 256), dim3(256), 0, stream>>>(qkv_w, wbuf, 196608 / 8);

    const int chunk_elems = W * NTOK * CDIM;          // multiple of 8
    for (int c = 0; c < nch; c++) {
        conv_bf16<<<dim3((chunk_elems / 8 + 255) / 256), dim3(256), 0, stream>>>(
            hidden + (size_t)c * chunk_elems, hbuf, chunk_elems / 8);
        qkv_gemm<<<dim3(W * NTOK / 128, 6), dim3(256), 0, stream>>>(
            hbuf, wbuf, qkv_b, qkvbuf);
        win_attn<<<dim3(W, NHEAD), dim3(64), 0, stream>>>(qkvbuf, comb, out, c * W);
    }
}

// Round 3
// 679.139 us; speedup vs baseline: 1.1444x; 1.1444x over previous
//
#include <hip/hip_runtime.h>
#include <hip/hip_bf16.h>
#include <stdint.h>

typedef unsigned short u16;
typedef __attribute__((ext_vector_type(8))) short bf16x8;          // 8 bf16 in 4 VGPRs
typedef __attribute__((ext_vector_type(8))) unsigned short u16x8;  // 16B store unit
typedef __attribute__((ext_vector_type(4))) float f32x4;

#define NTOK 49
#define CDIM 256
#define NHEAD 8
#define HDIM 32
#define SCALE_F 0.17677669529663687f  /* 32^-0.5 */

static __device__ inline u16 f2b(float f) {
    union { float f; unsigned u; } v; v.f = f;
    unsigned r = v.u + 0x7fff + ((v.u >> 16) & 1);   // RNE
    return (u16)(r >> 16);
}

// async global->LDS, 16B per lane; dest = wave-uniform base + lane*16
#define GLOAD_LDS16(g, l) __builtin_amdgcn_global_load_lds( \
    (const __attribute__((address_space(1))) unsigned int*)(g), \
    (__attribute__((address_space(3))) unsigned int*)(l), 16, 0, 0)

// ---------------------------------------------------------------------------
// fp32 -> bf16 converter, 8 elements/thread
// ---------------------------------------------------------------------------
__global__ __launch_bounds__(256) void conv_bf16(
    const float* __restrict__ src, u16* __restrict__ dst, int n8)
{
    int i = blockIdx.x * 256 + threadIdx.x;
    if (i < n8) {
        float4 a = ((const float4*)src)[2 * i];
        float4 b = ((const float4*)src)[2 * i + 1];
        u16x8 v;
        v[0] = f2b(a.x); v[1] = f2b(a.y); v[2] = f2b(a.z); v[3] = f2b(a.w);
        v[4] = f2b(b.x); v[5] = f2b(b.y); v[6] = f2b(b.z); v[7] = f2b(b.w);
        ((u16x8*)dst)[i] = v;
    }
}

// ---------------------------------------------------------------------------
// comb[m][h][64][64] = bias_table[rel_index[i,j], h] + mask[m,i,j], fp32.
// Padding (i>=49 || j>=49) = -1e9 so softmax sees exp(..)=0.
// ---------------------------------------------------------------------------
__global__ __launch_bounds__(256) void build_comb(
    const float* __restrict__ bias_table,   // [169,8] fp32
    const float* __restrict__ mask,         // [64,49,49] fp32
    const int*   __restrict__ rel_index,    // [49,49] int32
    float* __restrict__ comb)               // [64,8,64,64]
{
    int idx = blockIdx.x * 256 + threadIdx.x;       // 2097152
    int j = idx & 63, i = (idx >> 6) & 63, h = (idx >> 12) & 7, m = idx >> 15;
    float v = -1e9f;
    if (i < NTOK && j < NTOK) {
        int rel = rel_index[i * NTOK + j];
        v = bias_table[rel * NHEAD + h] + mask[m * (NTOK * NTOK) + i * NTOK + j];
    }
    comb[idx] = v;
}

// ---------------------------------------------------------------------------
// QKV projection: C[rows,768] = A[rows,256] @ W^T + b  (bf16 in, fp32 acc,
// bf16 out). 128x128 tile, BK=64, 4 waves (2x2), each wave 64x64 via 4x4
// mfma_f32_16x16x32_bf16. Staging via global_load_lds (16B) into an
// XOR-swizzled unpadded LDS layout: elem(row,col) at row*64 + ((col/8 ^
// (row&7))*8 + col%8 -> DMA stays lane-contiguous, frag ds_read_b128 is
// 2-way-bank-aliased only (free, m136).
// ---------------------------------------------------------------------------
__global__ __launch_bounds__(256) void qkv_gemm(
    const u16*  __restrict__ A,     // [rows,256] bf16
    const u16*  __restrict__ Wt,    // [768,256]  bf16
    const float* __restrict__ bias, // [768] fp32
    u16* __restrict__ Cout)         // [rows,768] bf16
{
    __shared__ u16 As[128 * 64];
    __shared__ u16 Bs[128 * 64];

    const int t = threadIdx.x;
    const int bm = blockIdx.x, bn = blockIdx.y;
    const int wave = t >> 6, lane = t & 63;
    const int wm = wave >> 1, wn = wave & 1;
    const int lrow = lane & 15, quad = lane >> 4;

    f32x4 acc[4][4];
#pragma unroll
    for (int i = 0; i < 4; i++)
#pragma unroll
        for (int j = 0; j < 4; j++) acc[i][j] = (f32x4){0.f, 0.f, 0.f, 0.f};

    // DMA source mapping: lane covers row (i*8 + lane/8), swizzled 16B chunk
    const int dr = lane >> 3;                 // 0..7
    const int dc = ((lane & 7) ^ dr) * 8;     // swizzled col (elems)
    const u16* Ag = A  + (size_t)(bm * 128 + wave * 32) * CDIM;
    const u16* Bg = Wt + (size_t)(bn * 128 + wave * 32) * CDIM;

#pragma unroll
    for (int kt = 0; kt < 4; kt++) {
        if (kt) __syncthreads();
        const int k0 = kt * 64;
#pragma unroll
        for (int i = 0; i < 4; i++) {
            GLOAD_LDS16(Ag + (size_t)(i * 8 + dr) * CDIM + k0 + dc, &As[(wave * 32 + i * 8) * 64]);
            GLOAD_LDS16(Bg + (size_t)(i * 8 + dr) * CDIM + k0 + dc, &Bs[(wave * 32 + i * 8) * 64]);
        }
        __syncthreads();   // drains vmcnt (DMA) before LDS reads
#pragma unroll
        for (int kk = 0; kk < 2; kk++) {
            const int xr = kk * 4 + quad;                 // 16B chunk index of kb
            const int sw = ((xr ^ (lrow & 7)) << 3);      // swizzled elem offset
            bf16x8 af[4], bfr[4];
#pragma unroll
            for (int tm = 0; tm < 4; tm++)
                af[tm] = *(const bf16x8*)&As[(wm * 64 + tm * 16 + lrow) * 64 + sw];
#pragma unroll
            for (int tn = 0; tn < 4; tn++)
                bfr[tn] = *(const bf16x8*)&Bs[(wn * 64 + tn * 16 + lrow) * 64 + sw];
#pragma unroll
            for (int tm = 0; tm < 4; tm++)
#pragma unroll
                for (int tn = 0; tn < 4; tn++)
                    acc[tm][tn] = __builtin_amdgcn_mfma_f32_16x16x32_bf16(
                        af[tm], bfr[tn], acc[tm][tn], 0, 0, 0);
        }
    }

    // epilogue: +bias, bf16 store. C/D layout: col=lane&15, row=quad*4+reg.
#pragma unroll
    for (int tn = 0; tn < 4; tn++) {
        int gcol = bn * 128 + wn * 64 + tn * 16 + lrow;
        float bv = bias[gcol];
#pragma unroll
        for (int tm = 0; tm < 4; tm++) {
            int grow0 = bm * 128 + wm * 64 + tm * 16 + quad * 4;
#pragma unroll
            for (int r = 0; r < 4; r++)
                Cout[(size_t)(grow0 + r) * 768 + gcol] = f2b(acc[tm][tn][r] + bv);
        }
    }
}

// ---------------------------------------------------------------------------
// Window attention v2: 1-wave blocks; grid (64 masks, NHEAD * G/4).
// Each wave: one (mask, head), 4 windows sharing the comb tile (held in
// 64 VGPRs, loaded once). Q/K fragments load directly from global (16B/lane
// row slices) -- no staging, no barriers. V transposed through LDS for the
// PV B-operand; P round-trips LDS (C-layout -> A-layout). Softmax skips
// max-subtraction (scores bounded; pad rows' NaNs stay in discarded rows).
// LDS 13.8 KB/block.
// ---------------------------------------------------------------------------
__global__ __launch_bounds__(64, 2) void win_attn(
    const u16*   __restrict__ qkv,   // [W*49, 768] bf16 chunk
    const float* __restrict__ comb,  // [64,8,64,64] fp32
    float* __restrict__ out,         // [W,49,256] fp32 chunk base
    int G4)                          // (windows per mask in chunk) / 4
{
    __shared__ u16 vT[32 * 72];      // 4608 B
    __shared__ u16 P[64 * 72];       // 9216 B

    const int lane = threadIdx.x, lrow = lane & 15, quad = lane >> 4;
    const int m = blockIdx.x;
    const int h = blockIdx.y / G4;
    const int grp = blockIdx.y % G4;
    const int qo = h * HDIM, ko = CDIM + h * HDIM, vo = 2 * CDIM + h * HDIM;

    // ---- comb tile -> registers (C-layout), loaded once for 4 windows ----
    f32x4 cmb[4][4];
    const float* cb = comb + (((size_t)m * NHEAD + h) << 12);
#pragma unroll
    for (int tm = 0; tm < 4; tm++)
#pragma unroll
        for (int r = 0; r < 4; r++) {
            const float* crow = cb + (tm * 16 + quad * 4 + r) * 64 + lrow;
#pragma unroll
            for (int tn = 0; tn < 4; tn++) cmb[tm][tn][r] = crow[tn * 16];
        }

    // zero vT pad cols (tokens 49..63) once
    for (int c = lane; c < 32 * 15; c += 64) vT[(c / 15) * 72 + NTOK + (c % 15)] = 0;

    for (int j = 0; j < 4; j++) {
        const int lw = m + 64 * (grp * 4 + j);
        const size_t rb = (size_t)lw * NTOK * 768;

        // ---- stage V transposed: [d][tok] ----
        for (int c = lane; c < NTOK * 8; c += 64) {
            int tok = c >> 3, d0 = (c & 7) * 4;
            uint2 v = *(const uint2*)&qkv[rb + (size_t)tok * 768 + vo + d0];
            vT[(d0 + 0) * 72 + tok] = (u16)(v.x & 0xffff);
            vT[(d0 + 1) * 72 + tok] = (u16)(v.x >> 16);
            vT[(d0 + 2) * 72 + tok] = (u16)(v.y & 0xffff);
            vT[(d0 + 3) * 72 + tok] = (u16)(v.y >> 16);
        }

        // ---- Q/K fragments direct from global ----
        bf16x8 af[4], bfr[4];
#pragma unroll
        for (int tm = 0; tm < 4; tm++)
            af[tm]  = *(const bf16x8*)&qkv[rb + (size_t)(tm * 16 + lrow) * 768 + qo + quad * 8];
#pragma unroll
        for (int tn = 0; tn < 4; tn++)
            bfr[tn] = *(const bf16x8*)&qkv[rb + (size_t)(tn * 16 + lrow) * 768 + ko + quad * 8];

        // ---- QK^T ----
        f32x4 s[4][4];
#pragma unroll
        for (int a = 0; a < 4; a++)
#pragma unroll
            for (int b = 0; b < 4; b++) s[a][b] = (f32x4){0.f, 0.f, 0.f, 0.f};
#pragma unroll
        for (int tm = 0; tm < 4; tm++)
#pragma unroll
            for (int tn = 0; tn < 4; tn++)
                s[tm][tn] = __builtin_amdgcn_mfma_f32_16x16x32_bf16(af[tm], bfr[tn], s[tm][tn], 0, 0, 0);

        // ---- scale + comb (registers) ----
#pragma unroll
        for (int tm = 0; tm < 4; tm++)
#pragma unroll
            for (int tn = 0; tn < 4; tn++)
#pragma unroll
                for (int r = 0; r < 4; r++)
                    s[tm][tn][r] = s[tm][tn][r] * SCALE_F + cmb[tm][tn][r];

        // ---- softmax (no max-subtract) + write normalized P (bf16) ----
#pragma unroll
        for (int tm = 0; tm < 4; tm++)
#pragma unroll
            for (int r = 0; r < 4; r++) {
                float e0 = __expf(s[tm][0][r]);
                float e1 = __expf(s[tm][1][r]);
                float e2 = __expf(s[tm][2][r]);
                float e3 = __expf(s[tm][3][r]);
                float sum = e0 + e1 + e2 + e3;
                sum += __shfl_xor(sum, 1);
                sum += __shfl_xor(sum, 2);
                sum += __shfl_xor(sum, 4);
                sum += __shfl_xor(sum, 8);
                float inv = 1.0f / sum;
                int i = tm * 16 + quad * 4 + r;
                P[i * 72 + lrow]      = f2b(e0 * inv);
                P[i * 72 + 16 + lrow] = f2b(e1 * inv);
                P[i * 72 + 32 + lrow] = f2b(e2 * inv);
                P[i * 72 + 48 + lrow] = f2b(e3 * inv);
            }

        // ---- PV ----
        f32x4 o[4][2];
#pragma unroll
        for (int a = 0; a < 4; a++) { o[a][0] = (f32x4){0.f,0.f,0.f,0.f}; o[a][1] = (f32x4){0.f,0.f,0.f,0.f}; }
#pragma unroll
        for (int kk = 0; kk < 2; kk++) {
            const int kb = kk * 32 + quad * 8;
            bf16x8 pf[4], vf[2];
#pragma unroll
            for (int tm = 0; tm < 4; tm++) pf[tm] = *(const bf16x8*)&P[(tm * 16 + lrow) * 72 + kb];
#pragma unroll
            for (int tn = 0; tn < 2; tn++) vf[tn] = *(const bf16x8*)&vT[(tn * 16 + lrow) * 72 + kb];
#pragma unroll
            for (int tm = 0; tm < 4; tm++)
#pragma unroll
                for (int tn = 0; tn < 2; tn++)
                    o[tm][tn] = __builtin_amdgcn_mfma_f32_16x16x32_bf16(pf[tm], vf[tn], o[tm][tn], 0, 0, 0);
        }

        // ---- store ctx (fp32) ----
        float* ob = out + (size_t)lw * NTOK * CDIM + h * HDIM;
#pragma unroll
        for (int tm = 0; tm < 4; tm++)
#pragma unroll
            for (int r = 0; r < 4; r++) {
                int i = tm * 16 + quad * 4 + r;
                if (i < NTOK) {
                    ob[(size_t)i * CDIM + lrow]      = o[tm][0][r];
                    ob[(size_t)i * CDIM + 16 + lrow] = o[tm][1][r];
                }
            }
    }
}

// ---------------------------------------------------------------------------
extern "C" void kernel_launch(void* const* d_in, const int* in_sizes, int n_in,
                              void* d_out, int out_size, void* d_ws, size_t ws_size,
                              hipStream_t stream) {
    const float* hidden     = (const float*)d_in[0];   // [4096,49,256] fp32
    const float* mask       = (const float*)d_in[1];   // [64,49,49]    fp32
    const float* qkv_w      = (const float*)d_in[2];   // [768,256]     fp32
    const float* qkv_b      = (const float*)d_in[3];   // [768]         fp32
    const float* bias_table = (const float*)d_in[4];   // [169,8]       fp32
    const int*   rel_index  = (const int*)d_in[5];     // [49,49]       int32
    float* out = (float*)d_out;

    // ws: comb fp32 | W bf16 | hidden-chunk bf16 | qkv-chunk bf16 | 64K slack
    float* comb = (float*)d_ws;                              // 8,388,608 B
    u16* wbuf = (u16*)((char*)d_ws + 8388608);               //   393,216 B
    int W = 4096;   // windows per chunk; multiple of 256 keeps all grids exact
    while (W > 256 &&
           8388608ull + 393216ull + (size_t)W * NTOK * CDIM * 2
                      + (size_t)W * NTOK * 768 * 2 + 65536ull > ws_size)
        W >>= 1;
    const int nch = 4096 / W;
    const int G4 = W / 256;                     // (W/64)/4 window-groups
    u16* hbuf = wbuf + 196608;
    u16* qkvbuf = hbuf + (size_t)W * NTOK * CDIM;

    build_comb<<<dim3(8192), dim3(256), 0, stream>>>(bias_table, mask, rel_index, comb);
    conv_bf16<<<dim3(96), dim3(256), 0, stream>>>(qkv_w, wbuf, 196608 / 8);

    const int ce = W * NTOK * CDIM;             // chunk elems (multiple of 8)
    for (int c = 0; c < nch; c++) {
        conv_bf16<<<dim3((ce / 8 + 255) / 256), dim3(256), 0, stream>>>(
            hidden + (size_t)c * ce, hbuf, ce / 8);
        qkv_gemm<<<dim3(W * NTOK / 128, 6), dim3(256), 0, stream>>>(
            hbuf, wbuf, qkv_b, qkvbuf);
        win_attn<<<dim3(64, NHEAD * G4), dim3(64), 0, stream>>>(
            qkvbuf, comb, out + (size_t)c * ce, G4);
    }
}